// Round 1
// baseline (309.310 us; speedup 1.0000x reference)
//
#include <hip/hip_runtime.h>
#include <hip/hip_bf16.h>
#include <stdint.h>

typedef unsigned short ushort_t;
typedef __attribute__((ext_vector_type(8))) short short8;
typedef __attribute__((ext_vector_type(4))) float floatx4;

// ---------- helpers ----------
__device__ __forceinline__ ushort_t f2bf(float f) {
    union { float f; unsigned u; } v; v.f = f;
    unsigned r = v.u + 0x7fffu + ((v.u >> 16) & 1u);   // RTNE
    return (ushort_t)(r >> 16);
}

__device__ __forceinline__ void async16(ushort_t* lds, const ushort_t* g) {
    __builtin_amdgcn_global_load_lds(
        (const __attribute__((address_space(1))) unsigned int*)g,
        (__attribute__((address_space(3))) unsigned int*)lds, 16, 0, 0);
}

// ---------- fp32 -> bf16 conversion of x ----------
__global__ __launch_bounds__(256) void cvt_bf16(const float* __restrict__ x,
                                                ushort_t* __restrict__ o, int n4) {
    int i = blockIdx.x * 256 + threadIdx.x;
    if (i < n4) {
        float4 v = ((const float4*)x)[i];
        ushort4 r;
        r.x = f2bf(v.x); r.y = f2bf(v.y); r.z = f2bf(v.z); r.w = f2bf(v.w);
        ((ushort4*)o)[i] = r;
    }
}

// ---------- A2[ii][k] = sum_r1 c0[r0,i0,r1]*c1[r1,i1,r2],  k=r0*16+r2 ----------
__global__ __launch_bounds__(256) void build_a2(const float* __restrict__ c0,
                                                const float* __restrict__ c1,
                                                float* __restrict__ A2) {
    int id = blockIdx.x * 256 + threadIdx.x;   // [0, 1024*256)
    int k = id & 255, ii = id >> 8;
    int r0 = k >> 4, r2 = k & 15;
    int i0 = ii >> 5, i1 = ii & 31;
    const float* p0 = c0 + (r0 * 32 + i0) * 16;   // stride 1 over r1
    const float* p1 = c1 + i1 * 16 + r2;          // stride 512 over r1
    float s = 0.f;
#pragma unroll
    for (int r1 = 0; r1 < 16; r1++) s += p0[r1] * p1[r1 * 512];
    A2[id] = s;                                   // A2[ii*256 + k]
}

// ---------- B2[k][oo] = sum_r3 c2[r2,o0,r3]*c3[r3,o1,r0],  oo=o0*64+o1 ----------
__global__ __launch_bounds__(256) void build_b2(const float* __restrict__ c2,
                                                const float* __restrict__ c3,
                                                float* __restrict__ B2) {
    int id = blockIdx.x * 256 + threadIdx.x;   // [0, 256*4096)
    int oo = id & 4095, k = id >> 12;
    int r0 = k >> 4, r2 = k & 15;
    int o0 = oo >> 6, o1 = oo & 63;
    const float* p2 = c2 + (r2 * 64 + o0) * 16;   // stride 1 over r3
    const float* p3 = c3 + o1 * 16 + r0;          // stride 1024 over r3
    float s = 0.f;
#pragma unroll
    for (int r3 = 0; r3 < 16; r3++) s += p2[r3] * p3[r3 * 1024];
    B2[id] = s;                                   // B2[k*4096 + oo]
}

// ---------- W[ii][oo] = sum_k A2[ii][k]*B2[k][oo] ; M=1024,N=4096,K=256 ----------
__global__ __launch_bounds__(256) void build_w(const float* __restrict__ A2,
                                               const float* __restrict__ B2,
                                               ushort_t* __restrict__ W) {
    __shared__ float As[64][33];   // +1 pad breaks 32-bank stride
    __shared__ float Bs[32][64];
    const int t = threadIdx.x;
    const int tx = t & 15, ty = t >> 4;
    const int ii0 = blockIdx.x * 64;   // grid.x = 16
    const int oo0 = blockIdx.y * 64;   // grid.y = 64
    float acc[4][4] = {};
    for (int kk = 0; kk < 256; kk += 32) {
#pragma unroll
        for (int j = 0; j < 2; j++) {
            int idx = t + j * 256;
            int r = idx >> 3, c = (idx & 7) * 4;           // A tile 64x32
            float4 v = *(const float4*)(A2 + (ii0 + r) * 256 + kk + c);
            As[r][c] = v.x; As[r][c + 1] = v.y; As[r][c + 2] = v.z; As[r][c + 3] = v.w;
            int kb = idx >> 4, cb = (idx & 15) * 4;        // B tile 32x64
            float4 u = *(const float4*)(B2 + (kk + kb) * 4096 + oo0 + cb);
            *(float4*)&Bs[kb][cb] = u;
        }
        __syncthreads();
#pragma unroll
        for (int k = 0; k < 32; k++) {
            float a[4], b[4];
#pragma unroll
            for (int i = 0; i < 4; i++) a[i] = As[ty * 4 + i][k];
#pragma unroll
            for (int j = 0; j < 4; j++) b[j] = Bs[k][tx + 16 * j];
#pragma unroll
            for (int i = 0; i < 4; i++)
#pragma unroll
                for (int j = 0; j < 4; j++) acc[i][j] += a[i] * b[j];
        }
        __syncthreads();
    }
#pragma unroll
    for (int i = 0; i < 4; i++)
#pragma unroll
        for (int j = 0; j < 4; j++)
            W[(size_t)(ii0 + ty * 4 + i) * 4096 + oo0 + tx + 16 * j] = f2bf(acc[i][j]);
}

// ---------- main GEMM: out[8192][4096] = Xb[8192][1024] * Wb[4096][1024]^T + bias ----------
// m97 structure: 128x128 tile, BK=32, 4 waves, 4x4 x (16x16x32) MFMA per wave.
__global__ __launch_bounds__(256) void gemm_bt_bias(const ushort_t* __restrict__ Xb,
                                                    const ushort_t* __restrict__ Wb,
                                                    const float* __restrict__ bias,
                                                    float* __restrict__ out) {
    __shared__ ushort_t As[128 * 32];   // [row][k] bf16 bits
    __shared__ ushort_t Bs[128 * 32];   // [n][k]   bf16 bits (B^T layout)
    const int t = threadIdx.x;
    const int row0 = blockIdx.x * 128;  // M (batch)
    const int col0 = blockIdx.y * 128;  // N (features)
    const int w = t >> 6, l = t & 63;
    const int wm = w >> 1, wn = w & 1;
    const int quad = l >> 4, ln = l & 15;

    floatx4 acc[4][4] = {};

    // staging source: thread t covers row t/4 (then +64), k-chunk (t&3)*8
    const ushort_t* aSrc = Xb + (size_t)(row0 + (t >> 2)) * 1024 + (t & 3) * 8;
    const ushort_t* bSrc = Wb + (size_t)(col0 + (t >> 2)) * 1024 + (t & 3) * 8;

    for (int kk = 0; kk < 1024; kk += 32) {
        async16(&As[t * 8],        aSrc + kk);
        async16(&As[2048 + t * 8], aSrc + 64 * 1024 + kk);
        async16(&Bs[t * 8],        bSrc + kk);
        async16(&Bs[2048 + t * 8], bSrc + 64 * 1024 + kk);
        __syncthreads();   // drains vmcnt -> LDS tiles complete

        short8 a[4], b[4];
#pragma unroll
        for (int ti = 0; ti < 4; ti++)
            a[ti] = *(const short8*)&As[(wm * 64 + ti * 16 + ln) * 32 + quad * 8];
#pragma unroll
        for (int tj = 0; tj < 4; tj++)
            b[tj] = *(const short8*)&Bs[(wn * 64 + tj * 16 + ln) * 32 + quad * 8];
#pragma unroll
        for (int ti = 0; ti < 4; ti++)
#pragma unroll
            for (int tj = 0; tj < 4; tj++)
                acc[ti][tj] = __builtin_amdgcn_mfma_f32_16x16x32_bf16(
                    a[ti], b[tj], acc[ti][tj], 0, 0, 0);
        __syncthreads();   // compute done before next-iter staging overwrites LDS
    }

    // epilogue: D layout col=lane&15, row=quad*4+reg  [m89]
#pragma unroll
    for (int tj = 0; tj < 4; tj++) {
        const int n = col0 + wn * 64 + tj * 16 + ln;
        const float bv = bias[n];
#pragma unroll
        for (int ti = 0; ti < 4; ti++) {
            const int m = row0 + wm * 64 + ti * 16 + quad * 4;
            float* o = out + (size_t)m * 4096 + n;
#pragma unroll
            for (int r = 0; r < 4; r++)
                o[(size_t)r * 4096] = acc[ti][tj][r] + bv;
        }
    }
}

extern "C" void kernel_launch(void* const* d_in, const int* in_sizes, int n_in,
                              void* d_out, int out_size, void* d_ws, size_t ws_size,
                              hipStream_t stream) {
    const float* x    = (const float*)d_in[0];   // 8192*1024
    const float* c0   = (const float*)d_in[1];   // 16*32*16
    const float* c1   = (const float*)d_in[2];   // 16*32*16
    const float* c2   = (const float*)d_in[3];   // 16*64*16
    const float* c3   = (const float*)d_in[4];   // 16*64*16
    const float* bias = (const float*)d_in[5];   // 4096
    float* out = (float*)d_out;                  // 8192*4096

    char* ws = (char*)d_ws;
    ushort_t* Xb = (ushort_t*)ws;                         // 16 MB  bf16 x
    ushort_t* Wb = (ushort_t*)(ws + (16u << 20));         //  8 MB  bf16 W (4096x1024)
    float*    A2 = (float*)(ws + (24u << 20));            //  1 MB
    float*    B2 = (float*)(ws + (25u << 20));            //  4 MB

    hipLaunchKernelGGL(cvt_bf16, dim3(8192), dim3(256), 0, stream, x, Xb, 8192 * 1024 / 4);
    hipLaunchKernelGGL(build_a2, dim3(1024), dim3(256), 0, stream, c0, c1, A2);
    hipLaunchKernelGGL(build_b2, dim3(4096), dim3(256), 0, stream, c2, c3, B2);
    hipLaunchKernelGGL(build_w,  dim3(16, 64), dim3(256), 0, stream, A2, B2, Wb);
    hipLaunchKernelGGL(gemm_bt_bias, dim3(64, 32), dim3(256), 0, stream, Xb, Wb, bias, out);
}

// Round 2
// 255.058 us; speedup vs baseline: 1.2127x; 1.2127x over previous
//
#include <hip/hip_runtime.h>
#include <hip/hip_bf16.h>
#include <stdint.h>

typedef unsigned short ushort_t;
typedef __attribute__((ext_vector_type(8))) short short8;
typedef __attribute__((ext_vector_type(4))) float floatx4;

// ---------- helpers ----------
__device__ __forceinline__ ushort_t f2bf(float f) {
    union { float f; unsigned u; } v; v.f = f;
    unsigned r = v.u + 0x7fffu + ((v.u >> 16) & 1u);   // RTNE
    return (ushort_t)(r >> 16);
}

__device__ __forceinline__ void async16(ushort_t* lds, const ushort_t* g) {
    __builtin_amdgcn_global_load_lds(
        (const __attribute__((address_space(1))) unsigned int*)g,
        (__attribute__((address_space(3))) unsigned int*)lds, 16, 0, 0);
}

// ---------- fused prep: cvt x -> bf16, A2b[ii][k], B2t[oo][k] (bf16) ----------
// blocks [0,8192): cvt; [8192,9216): A2; [9216,13312): B2t
__global__ __launch_bounds__(256) void prep_all(const float* __restrict__ x,
                                                const float* __restrict__ c0,
                                                const float* __restrict__ c1,
                                                const float* __restrict__ c2,
                                                const float* __restrict__ c3,
                                                ushort_t* __restrict__ Xb,
                                                ushort_t* __restrict__ A2b,
                                                ushort_t* __restrict__ B2t) {
    const int b = blockIdx.x, t = threadIdx.x;
    if (b < 8192) {
        int i = b * 256 + t;                       // float4 index, n4 = 2M
        float4 v = ((const float4*)x)[i];
        ushort4 r;
        r.x = f2bf(v.x); r.y = f2bf(v.y); r.z = f2bf(v.z); r.w = f2bf(v.w);
        ((ushort4*)Xb)[i] = r;
    } else if (b < 9216) {
        // A2[ii][k] = sum_r1 c0[r0,i0,r1]*c1[r1,i1,r2], k = r0*16+r2
        int id = (b - 8192) * 256 + t;             // [0, 1024*256)
        int k = id & 255, ii = id >> 8;
        int r0 = k >> 4, r2 = k & 15;
        int i0 = ii >> 5, i1 = ii & 31;
        const float* p0 = c0 + (r0 * 32 + i0) * 16;   // stride 1 over r1
        const float* p1 = c1 + i1 * 16 + r2;          // stride 512 over r1
        float s = 0.f;
#pragma unroll
        for (int r1 = 0; r1 < 16; r1++) s += p0[r1] * p1[r1 * 512];
        A2b[id] = f2bf(s);                         // A2b[ii*256 + k], k-coalesced
    } else {
        // B2t[oo][k] = sum_r3 c2[r2,o0,r3]*c3[r3,o1,r0], k = r0*16+r2
        int id = (b - 9216) * 256 + t;             // [0, 4096*256)
        int k = id & 255, oo = id >> 8;
        int r0 = k >> 4, r2 = k & 15;
        int o0 = oo >> 6, o1 = oo & 63;
        const float* p2 = c2 + (r2 * 64 + o0) * 16;   // stride 1 over r3
        const float* p3 = c3 + o1 * 16 + r0;          // stride 1024 over r3
        float s = 0.f;
#pragma unroll
        for (int r3 = 0; r3 < 16; r3++) s += p2[r3] * p3[r3 * 1024];
        B2t[id] = f2bf(s);                         // B2t[oo*256 + k], k-coalesced
    }
}

// ---------- W build as MFMA GEMM: Wb[ii*4096+oo] = sum_k A2[ii][k]*B2t[oo][k]
// M=1024 (ii), N=4096 (oo), K=256. m97 structure, 128x128 tile, grid (8,32).
// NOTE: flat layout Wb[ii*4096+oo] is load-bearing — reinterpreted as the
// reference's row-major (4096,1024) w_mat by the main GEMM.
__global__ __launch_bounds__(256) void build_w_mfma(const ushort_t* __restrict__ A2b,
                                                    const ushort_t* __restrict__ B2t,
                                                    ushort_t* __restrict__ W) {
    __shared__ ushort_t As[128 * 32];
    __shared__ ushort_t Bs[128 * 32];
    const int t = threadIdx.x;
    const int row0 = blockIdx.x * 128;  // ii
    const int col0 = blockIdx.y * 128;  // oo
    const int w = t >> 6, l = t & 63;
    const int wm = w >> 1, wn = w & 1;
    const int quad = l >> 4, ln = l & 15;

    floatx4 acc[4][4] = {};

    const ushort_t* aSrc = A2b + (size_t)(row0 + (t >> 2)) * 256 + (t & 3) * 8;
    const ushort_t* bSrc = B2t + (size_t)(col0 + (t >> 2)) * 256 + (t & 3) * 8;

    for (int kk = 0; kk < 256; kk += 32) {
        async16(&As[t * 8],        aSrc + kk);
        async16(&As[2048 + t * 8], aSrc + 64 * 256 + kk);
        async16(&Bs[t * 8],        bSrc + kk);
        async16(&Bs[2048 + t * 8], bSrc + 64 * 256 + kk);
        __syncthreads();

        short8 a[4], b[4];
#pragma unroll
        for (int ti = 0; ti < 4; ti++)
            a[ti] = *(const short8*)&As[(wm * 64 + ti * 16 + ln) * 32 + quad * 8];
#pragma unroll
        for (int tj = 0; tj < 4; tj++)
            b[tj] = *(const short8*)&Bs[(wn * 64 + tj * 16 + ln) * 32 + quad * 8];
#pragma unroll
        for (int ti = 0; ti < 4; ti++)
#pragma unroll
            for (int tj = 0; tj < 4; tj++)
                acc[ti][tj] = __builtin_amdgcn_mfma_f32_16x16x32_bf16(
                    a[ti], b[tj], acc[ti][tj], 0, 0, 0);
        __syncthreads();
    }

#pragma unroll
    for (int tj = 0; tj < 4; tj++) {
        const int n = col0 + wn * 64 + tj * 16 + ln;
#pragma unroll
        for (int ti = 0; ti < 4; ti++) {
            const int m = row0 + wm * 64 + ti * 16 + quad * 4;
#pragma unroll
            for (int r = 0; r < 4; r++)
                W[(size_t)(m + r) * 4096 + n] = f2bf(acc[ti][tj][r]);
        }
    }
}

// ---------- main GEMM: out[8192][4096] = Xb[8192][1024] * Wb(4096x1024)^T + bias ----------
__global__ __launch_bounds__(256) void gemm_bt_bias(const ushort_t* __restrict__ Xb,
                                                    const ushort_t* __restrict__ Wb,
                                                    const float* __restrict__ bias,
                                                    float* __restrict__ out) {
    __shared__ ushort_t As[128 * 32];
    __shared__ ushort_t Bs[128 * 32];
    const int t = threadIdx.x;
    const int row0 = blockIdx.x * 128;  // M (batch)
    const int col0 = blockIdx.y * 128;  // N (features)
    const int w = t >> 6, l = t & 63;
    const int wm = w >> 1, wn = w & 1;
    const int quad = l >> 4, ln = l & 15;

    floatx4 acc[4][4] = {};

    const ushort_t* aSrc = Xb + (size_t)(row0 + (t >> 2)) * 1024 + (t & 3) * 8;
    const ushort_t* bSrc = Wb + (size_t)(col0 + (t >> 2)) * 1024 + (t & 3) * 8;

    for (int kk = 0; kk < 1024; kk += 32) {
        async16(&As[t * 8],        aSrc + kk);
        async16(&As[2048 + t * 8], aSrc + 64 * 1024 + kk);
        async16(&Bs[t * 8],        bSrc + kk);
        async16(&Bs[2048 + t * 8], bSrc + 64 * 1024 + kk);
        __syncthreads();

        short8 a[4], b[4];
#pragma unroll
        for (int ti = 0; ti < 4; ti++)
            a[ti] = *(const short8*)&As[(wm * 64 + ti * 16 + ln) * 32 + quad * 8];
#pragma unroll
        for (int tj = 0; tj < 4; tj++)
            b[tj] = *(const short8*)&Bs[(wn * 64 + tj * 16 + ln) * 32 + quad * 8];
#pragma unroll
        for (int ti = 0; ti < 4; ti++)
#pragma unroll
            for (int tj = 0; tj < 4; tj++)
                acc[ti][tj] = __builtin_amdgcn_mfma_f32_16x16x32_bf16(
                    a[ti], b[tj], acc[ti][tj], 0, 0, 0);
        __syncthreads();
    }

    // epilogue: D layout col=lane&15, row=quad*4+reg  [m89]
#pragma unroll
    for (int tj = 0; tj < 4; tj++) {
        const int n = col0 + wn * 64 + tj * 16 + ln;
        const float bv = bias[n];
#pragma unroll
        for (int ti = 0; ti < 4; ti++) {
            const int m = row0 + wm * 64 + ti * 16 + quad * 4;
            float* o = out + (size_t)m * 4096 + n;
#pragma unroll
            for (int r = 0; r < 4; r++)
                o[(size_t)r * 4096] = acc[ti][tj][r] + bv;
        }
    }
}

extern "C" void kernel_launch(void* const* d_in, const int* in_sizes, int n_in,
                              void* d_out, int out_size, void* d_ws, size_t ws_size,
                              hipStream_t stream) {
    const float* x    = (const float*)d_in[0];   // 8192*1024
    const float* c0   = (const float*)d_in[1];   // 16*32*16
    const float* c1   = (const float*)d_in[2];   // 16*32*16
    const float* c2   = (const float*)d_in[3];   // 16*64*16
    const float* c3   = (const float*)d_in[4];   // 16*64*16
    const float* bias = (const float*)d_in[5];   // 4096
    float* out = (float*)d_out;                  // 8192*4096

    char* ws = (char*)d_ws;
    ushort_t* Xb  = (ushort_t*)ws;                        // 16 MB bf16 x
    ushort_t* Wb  = (ushort_t*)(ws + (16u << 20));        //  8 MB bf16 W flat [ii*4096+oo]
    ushort_t* A2b = (ushort_t*)(ws + (24u << 20));        // 0.5 MB bf16 A2[ii][k]
    ushort_t* B2t = (ushort_t*)(ws + (25u << 20));        //  2 MB bf16 B2t[oo][k]

    hipLaunchKernelGGL(prep_all, dim3(13312), dim3(256), 0, stream,
                       x, c0, c1, c2, c3, Xb, A2b, B2t);
    hipLaunchKernelGGL(build_w_mfma, dim3(8, 32), dim3(256), 0, stream, A2b, B2t, Wb);
    hipLaunchKernelGGL(gemm_bt_bias, dim3(64, 32), dim3(256), 0, stream, Xb, Wb, bias, out);
}